// Round 11
// baseline (226.660 us; speedup 1.0000x reference)
//
#include <hip/hip_runtime.h>
#include <stdint.h>

// DeformableFusionAcrossFocus — round 16: two-tile-per-block pipeline assembled
// ONLY from hardware-verified components.
// x:(2,64,16,96,96) f32 | w_off:(6,64,3) | b_off:(6) | w_def:(64,64,3) | b_def:(64) -> out f32
// Grid 576 x 512 thr: block owns w0 = (tn%3)*32 — a full 128B line — processed as
// two 16-wide tiles (j=0: w0, j=1: w0+16). Per-tile phase code = r15 VERBATIM
// (passed, 67µs): float4 stage -> bf16 pack -> LDS transpose -> MFMA offsets conv
// -> interp -> unrolled GEMM -> direct stores.
// Pipeline (r8-verified pieces): tile-2's 8 float4 loads issued after tile-1's
// transpose barrier + sched_barrier(0) -> HBM latency hides under tile-1 compute.
// Write pairing now INTRA-BLOCK: same block writes both 64B halves of each out
// line ~15µs apart -> merge in that XCD's 4MB L2 (no cross-block timing dependence,
// no swizzle needed). r14's novelties all removed: no lambdas, no combined epilogue,
// no acc held across tiles (VGPR ~96 < 128 cap, no spill), offs in its OWN region
// (r8-verified; no overlay reasoning across tiles).
// LDS: xs_t 36864 + xstage 32768 + offs 6144 = 75776 -> 2 blocks/CU.

typedef __attribute__((ext_vector_type(8))) short short8;
typedef __attribute__((ext_vector_type(4))) float f32x4;
typedef __attribute__((ext_vector_type(2))) float f32x2;
typedef __attribute__((ext_vector_type(4))) unsigned int u32x4;

// LDS (bytes), disjoint regions, no overlays:
//  [0,36864)      xs_t bf16 [pos][72 shorts] (row stride 144B; 64 c used + 8 pad)
//  [36864,69632)  xstage bf16 [c*256 + pos]
//  [69632,75776)  offs f32 [6][256] (same-wave produce/consume)
#define XT_OFF   0
#define XG_OFF   36864
#define OFFS_OFF 69632
#define LDS_BYTES 75776   // 2 blocks/CU: 2*75776 = 151552 <= 163840

__device__ __forceinline__ short f2bf(float f) {
  union { float f; uint32_t u; } v; v.f = f;
  uint32_t r = (v.u + 0x7FFFu + ((v.u >> 16) & 1u)) >> 16;
  return (short)r;
}
__device__ __forceinline__ float asf(uint32_t u) {
  union { uint32_t u; float f; } v; v.u = u; return v.f;
}
__device__ __forceinline__ uint32_t cvt_pk_bf16(float lo, float hi) {
  uint32_t d;
  asm("v_cvt_pk_bf16_f32 %0, %1, %2" : "=v"(d) : "v"(lo), "v"(hi));
  return d;
}

// ---- prep: pre-swizzle w_def (frags [0,1536)) and w_off (frags [1536,1920)) into ws ----
__global__ __launch_bounds__(256) void prep_kernel(
    const float* __restrict__ w_off, const float* __restrict__ w_def, short8* __restrict__ ws)
{
  int gid = blockIdx.x * 256 + threadIdx.x;
  if (gid < 1536) {                      // q = (mt*6+ks)*64 + lane
    int mt = gid / 384, ks = (gid % 384) >> 6, ll = gid & 63;
    int m = mt * 16 + (ll & 15), rgq = ll >> 4;
    short8 v;
    #pragma unroll
    for (int jj = 0; jj < 8; ++jj) {
      int kk = ks * 32 + rgq * 8 + jj;
      int c = kk & 63, k3 = kk >> 6;
      v[jj] = f2bf(w_def[m * 192 + c * 3 + k3]);
    }
    ws[gid] = v;
  } else if (gid < 1920) {               // q = ks*64 + lane (rows 6..15 zero)
    int q = gid - 1536;
    int ks = q >> 6, ll = q & 63;
    int m = ll & 15, rgq = ll >> 4;
    short8 v;
    #pragma unroll
    for (int jj = 0; jj < 8; ++jj) {
      int kk = ks * 32 + rgq * 8 + jj;
      int c = kk & 63, k3 = kk >> 6;
      v[jj] = (m < 6) ? f2bf(w_off[m * 192 + c * 3 + k3]) : (short)0;
    }
    ws[gid] = v;
  }
}

__global__ __launch_bounds__(512, 4) void deform_main(
    const float* __restrict__ x, const float* __restrict__ b_off,
    const float* __restrict__ b_def, const short8* __restrict__ wfr,
    float* __restrict__ out)
{
  extern __shared__ char smem[];
  uint16_t* xst = (uint16_t*)(smem + XG_OFF);
  float* offs   = (float*)(smem + OFFS_OFF);

  const int t = threadIdx.x, wv = t >> 6, l = t & 63, col = l & 15, rg = l >> 4;
  const int tn = blockIdx.x;
  const int wt2 = tn % 3, bh = tn / 3;
  const int h = bh % 96, b = bh / 96, w0 = wt2 * 32;
  const float* xb = x + (size_t)b * 9437184 + h * 96 + w0;
  float* ob       = out + (size_t)b * 9437184 + h * 96 + w0;

  float4 v[8];

  // ---- prologue: load tile 0 (w0..w0+15) ----
  #pragma unroll
  for (int i = 0; i < 8; ++i) {
    int r = (t >> 2) + i * 128, quad = t & 3;       // r = c*16+n, 4 lanes per 64B row
    v[i] = *(const float4*)(xb + (size_t)r * 9216 + quad * 4);
  }

  #pragma unroll
  for (int j = 0; j < 2; ++j) {
    // ---- stage v -> bf16 xstage [c][pos] ----
    #pragma unroll
    for (int i = 0; i < 8; ++i) {
      int r = (t >> 2) + i * 128, quad = t & 3;
      uint2 pk;
      pk.x = cvt_pk_bf16(v[i].x, v[i].y);
      pk.y = cvt_pk_bf16(v[i].z, v[i].w);
      *(uint2*)(xst + r * 16 + quad * 4) = pk;      // xstage idx = c*256 + n*16 + quad*4
    }
    __syncthreads();

    // ---- transpose -> xs_t[pos][c] (b128 writes; stride 144B) ----
    #pragma unroll
    for (int i = 0; i < 4; ++i) {
      int item = t + 512 * i;                // 2048 = 256 pos x 8 cgroups
      int pos = item & 255, cg = item >> 8;
      short8 vv;
      #pragma unroll
      for (int jj = 0; jj < 8; ++jj) vv[jj] = (short)xst[(cg * 8 + jj) * 256 + pos];
      *(short8*)(smem + XT_OFF + pos * 144 + cg * 16) = vv;
    }
    __syncthreads();   // xs_t complete

    if (j == 0) {
      // ---- prefetch tile 1 (w0+16..w0+31); hides under tile-0 compute ----
      #pragma unroll
      for (int i = 0; i < 8; ++i) {
        int r = (t >> 2) + i * 128, quad = t & 3;
        v[i] = *(const float4*)(xb + 16 + (size_t)r * 9216 + quad * 4);
      }
      __builtin_amdgcn_sched_barrier(0);   // pin load issue above the compute
    }

    // ---- offsets conv via MFMA; offs produced & consumed by the SAME wave ----
    {
      f32x4 cacc[2] = {{0.f,0.f,0.f,0.f},{0.f,0.f,0.f,0.f}};
      const short8 zero = {0,0,0,0,0,0,0,0};
      #pragma unroll
      for (int ks = 0; ks < 6; ++ks) {
        short8 av = wfr[1536 + ks * 64 + l];
        int k3 = ks >> 1;
        #pragma unroll
        for (int nt2 = 0; nt2 < 2; ++nt2) {
          int n = wv * 2 + nt2;              // pos = n*16 + col
          int row = n + k3 - 1;
          bool valid = (row >= 0) && (row < 16);
          int rcl = min(max(row, 0), 15);
          short8 bv = *(short8*)(smem + XT_OFF + (rcl * 16 + col) * 144 + rg * 16 + (ks & 1) * 64);
          bv = valid ? bv : zero;
          cacc[nt2] = __builtin_amdgcn_mfma_f32_16x16x32_bf16(av, bv, cacc[nt2], 0, 0, 0);
        }
      }
      #pragma unroll
      for (int nt2 = 0; nt2 < 2; ++nt2) {
        int pos = (wv * 2 + nt2) * 16 + col;
        #pragma unroll
        for (int r = 0; r < 4; ++r) {
          int rowo = rg * 4 + r;
          if (rowo < 6) offs[rowo * 256 + pos] = cacc[nt2][r];
        }
      }
    }
    // no barrier: same-wave LDS ordering suffices (offs pos ranges are per-wave)

    // ---- interp params, per-lane in registers (all loop indices constant) ----
    float a0v[3][2], a1v[3][2]; int rb[3][2];
    #pragma unroll
    for (int k = 0; k < 3; ++k) {
      #pragma unroll
      for (int nt2 = 0; nt2 < 2; ++nt2) {
        int n = wv * 2 + nt2;
        int pos = n * 16 + col;
        float oy = offs[(2 * k) * 256 + pos] + b_off[2 * k];
        float ox = offs[(2 * k + 1) * 256 + pos] + b_off[2 * k + 1];
        float px = (float)(n - 1 + k) + ox;
        float x0f = floorf(px);
        float fx = px - x0f;
        int x0 = (int)x0f;
        float wy = fmaxf(0.f, 1.f - fabsf(oy));
        float wt1v = fx * wy;
        float wt0v = wy - wt1v;
        float a0, a1; int r0;
        if (x0 >= 0 && x0 < 15)  { r0 = x0; a0 = wt0v; a1 = wt1v; }
        else if (x0 == 15)       { r0 = 14; a0 = 0.f;  a1 = wt0v; }  // only row 15 (=x0)
        else if (x0 == -1)       { r0 = 0;  a0 = wt1v; a1 = 0.f;  }  // only row 0 (=x1)
        else                     { r0 = 0;  a0 = 0.f;  a1 = 0.f;  }
        a0v[k][nt2] = a0; a1v[k][nt2] = a1;
        rb[k][nt2] = (r0 * 16 + col) * 144;
      }
    }

    // ---- main GEMM: 64 o x 32 pos per wave, K=192; fully unrolled ----
    f32x4 acc[4][2];
    #pragma unroll
    for (int mt = 0; mt < 4; ++mt) {
      float4 bd = *(const float4*)(b_def + mt * 16 + rg * 4);
      #pragma unroll
      for (int nt2 = 0; nt2 < 2; ++nt2) {
        acc[mt][nt2][0] = bd.x; acc[mt][nt2][1] = bd.y;
        acc[mt][nt2][2] = bd.z; acc[mt][nt2][3] = bd.w;
      }
    }
    #pragma unroll
    for (int k3 = 0; k3 < 3; ++k3) {
      #pragma unroll
      for (int ks2 = 0; ks2 < 2; ++ks2) {
        int ks = k3 * 2 + ks2;
        short8 A[4];
        #pragma unroll
        for (int mt = 0; mt < 4; ++mt) A[mt] = wfr[(mt * 6 + ks) * 64 + l];
        #pragma unroll
        for (int nt2 = 0; nt2 < 2; ++nt2) {
          const char* base = smem + XT_OFF + rb[k3][nt2] + rg * 16 + ks2 * 64;
          u32x4 x0 = *(const u32x4*)base;
          u32x4 x1 = *(const u32x4*)(base + 2304);   // tap row r0+1 (16 pos x stride 144)
          f32x2 A0 = {a0v[k3][nt2], a0v[k3][nt2]};
          f32x2 A1 = {a1v[k3][nt2], a1v[k3][nt2]};
          union { uint32_t w[4]; short8 s; } bu;
          #pragma unroll
          for (int q = 0; q < 4; ++q) {
            uint32_t u0 = x0[q], u1 = x1[q];
            f32x2 X0 = { asf(u0 << 16), asf(u0 & 0xffff0000u) };
            f32x2 X1 = { asf(u1 << 16), asf(u1 & 0xffff0000u) };
            f32x2 R = A0 * X0 + A1 * X1;
            bu.w[q] = cvt_pk_bf16(R.x, R.y);
          }
          short8 bv = bu.s;
          #pragma unroll
          for (int mt = 0; mt < 4; ++mt)
            acc[mt][nt2] = __builtin_amdgcn_mfma_f32_16x16x32_bf16(A[mt], bv, acc[mt][nt2], 0, 0, 0);
        }
      }
    }

    // ---- epilogue (per tile): direct stores; this block writes the other 64B
    //      half of every 128B line next iteration -> intra-block L2 merge ----
    {
      float* obj = ob + j * 16;
      #pragma unroll
      for (int mt = 0; mt < 4; ++mt) {
        #pragma unroll
        for (int nt2 = 0; nt2 < 2; ++nt2) {
          int n = wv * 2 + nt2;
          float* o0 = obj + (size_t)((mt * 16 + rg * 4) * 16 + n) * 9216 + col;
          #pragma unroll
          for (int r = 0; r < 4; ++r)
            o0[(size_t)r * 147456] = acc[mt][nt2][r];   // o stride = 16*9216
        }
      }
    }

    if (j == 0)
      __syncthreads();   // tile-0 xs_t/offs reads done before tile-1 overwrites
  }
}

extern "C" void kernel_launch(void* const* d_in, const int* in_sizes, int n_in,
                              void* d_out, int out_size, void* d_ws, size_t ws_size,
                              hipStream_t stream) {
  (void)in_sizes; (void)n_in; (void)ws_size; (void)out_size;
  const float* x     = (const float*)d_in[0];
  const float* w_off = (const float*)d_in[1];
  const float* b_off = (const float*)d_in[2];
  const float* w_def = (const float*)d_in[3];
  const float* b_def = (const float*)d_in[4];
  float* out = (float*)d_out;
  short8* wfr = (short8*)d_ws;   // 1920 * 16B = 30720 B of scratch

  (void)hipFuncSetAttribute((const void*)deform_main,
                            hipFuncAttributeMaxDynamicSharedMemorySize, LDS_BYTES);
  prep_kernel<<<dim3(8), dim3(256), 0, stream>>>(w_off, w_def, wfr);
  deform_main<<<dim3(576), dim3(512), LDS_BYTES, stream>>>(x, b_off, b_def, wfr, out);
}

// Round 12
// 225.803 us; speedup vs baseline: 1.0038x; 1.0038x over previous
//
#include <hip/hip_runtime.h>
#include <stdint.h>

// DeformableFusionAcrossFocus — round 17: persistent blocks + atomic work-stealing.
// x:(2,64,16,96,96) f32 | w_off:(6,64,3) | b_off:(6) | w_def:(64,64,3) | b_def:(64) -> out f32
// Grid 512 blocks x 512 thr (EXACTLY 2/CU, all resident, zero tail rounds); each
// block grabs tiles (tn in [0,1152), 16-wide: wt=tn%6, bh=tn/6) from a global
// atomic counter until exhausted.
// Why (r16 post-mortem): (1) static 576x2 grid left a 64-block tail = +55us idle
// machine; work-stealing balances by TIME (+-1 tile). (2) 64B half-line writes
// merge only if written ~concurrently (r9/r15 clean vs r8/r13/r16 dirty): linear
// tn means consecutive GRABS = adjacent halves of one 128B line, grabbed ~1us
// apart -> concurrent writes, robust merge without any XCD swizzle.
// (3) blocks de-phase as they proceed -> continuous HBM flow (kills the r0
// duty-cycle stall), plus r16-verified prefetch: grab tile j+1 after staging j,
// issue its 8 float4 loads before the transpose -> ~900cy latency hidden.
// Per-tile phase code = r15 VERBATIM (passed, 67.5us). New mechanics: lane-0
// atomicAdd + LDS broadcast folded into existing barriers; 3 barriers/tile.
// Counter at d_ws+30720, zeroed by prep_kernel (same stream, graph-safe).
// LDS 69648 (r15's 69632 + 16B tn slot) -> 2 blocks/CU.

typedef __attribute__((ext_vector_type(8))) short short8;
typedef __attribute__((ext_vector_type(4))) float f32x4;
typedef __attribute__((ext_vector_type(2))) float f32x2;
typedef __attribute__((ext_vector_type(4))) unsigned int u32x4;

// LDS (bytes):
//  [0,36864)      xs_t bf16 [pos][72 shorts] (row stride 144B; 64 c used + 8 pad)
//  [36864,69632)  xstage bf16 [c*256 + pos] (dead after transpose)
//  [36864,43008)  offs f32 [6][256] (overlays dead xstage; same-wave produce/consume)
//  [69632,69648)  tn broadcast slot
#define XT_OFF   0
#define XG_OFF   36864
#define OFFS_OFF 36864
#define TN_OFF   69632
#define LDS_BYTES 69648   // 2 blocks/CU: 2*69648 = 139296 <= 163840

#define NTILES 1152

__device__ __forceinline__ short f2bf(float f) {
  union { float f; uint32_t u; } v; v.f = f;
  uint32_t r = (v.u + 0x7FFFu + ((v.u >> 16) & 1u)) >> 16;
  return (short)r;
}
__device__ __forceinline__ float asf(uint32_t u) {
  union { uint32_t u; float f; } v; v.u = u; return v.f;
}
__device__ __forceinline__ uint32_t cvt_pk_bf16(float lo, float hi) {
  uint32_t d;
  asm("v_cvt_pk_bf16_f32 %0, %1, %2" : "=v"(d) : "v"(lo), "v"(hi));
  return d;
}

// ---- prep: pre-swizzle w_def/w_off into ws frags; zero the work counter ----
__global__ __launch_bounds__(256) void prep_kernel(
    const float* __restrict__ w_off, const float* __restrict__ w_def,
    short8* __restrict__ ws, unsigned int* __restrict__ ctr)
{
  int gid = blockIdx.x * 256 + threadIdx.x;
  if (gid == 0) ctr[0] = 0u;
  if (gid < 1536) {                      // q = (mt*6+ks)*64 + lane
    int mt = gid / 384, ks = (gid % 384) >> 6, ll = gid & 63;
    int m = mt * 16 + (ll & 15), rgq = ll >> 4;
    short8 v;
    #pragma unroll
    for (int jj = 0; jj < 8; ++jj) {
      int kk = ks * 32 + rgq * 8 + jj;
      int c = kk & 63, k3 = kk >> 6;
      v[jj] = f2bf(w_def[m * 192 + c * 3 + k3]);
    }
    ws[gid] = v;
  } else if (gid < 1920) {               // q = ks*64 + lane (rows 6..15 zero)
    int q = gid - 1536;
    int ks = q >> 6, ll = q & 63;
    int m = ll & 15, rgq = ll >> 4;
    short8 v;
    #pragma unroll
    for (int jj = 0; jj < 8; ++jj) {
      int kk = ks * 32 + rgq * 8 + jj;
      int c = kk & 63, k3 = kk >> 6;
      v[jj] = (m < 6) ? f2bf(w_off[m * 192 + c * 3 + k3]) : (short)0;
    }
    ws[gid] = v;
  }
}

__global__ __launch_bounds__(512, 4) void deform_main(
    const float* __restrict__ x, const float* __restrict__ b_off,
    const float* __restrict__ b_def, const short8* __restrict__ wfr,
    float* __restrict__ out, unsigned int* __restrict__ ctr)
{
  extern __shared__ char smem[];
  uint16_t* xst = (uint16_t*)(smem + XG_OFF);
  float* offs   = (float*)(smem + OFFS_OFF);
  int* tn_lds   = (int*)(smem + TN_OFF);

  const int t = threadIdx.x, wv = t >> 6, l = t & 63, col = l & 15, rg = l >> 4;

  float4 v[8];

  // ---- prologue: grab first tile, start its loads ----
  if (t == 0) tn_lds[0] = (int)atomicAdd(ctr, 1u);
  __syncthreads();
  int tn = tn_lds[0];
  if (tn < NTILES) {
    int wt = tn % 6, bh = tn / 6;
    const float* xb = x + (size_t)(bh / 96) * 9437184 + (bh % 96) * 96 + wt * 16;
    #pragma unroll
    for (int i = 0; i < 8; ++i) {
      int r = (t >> 2) + i * 128, quad = t & 3;     // r = c*16+n, 4 lanes per 64B row
      v[i] = *(const float4*)(xb + (size_t)r * 9216 + quad * 4);
    }
  }

  while (tn < NTILES) {
    // ---- stage v -> bf16 xstage [c][pos] ----
    #pragma unroll
    for (int i = 0; i < 8; ++i) {
      int r = (t >> 2) + i * 128, quad = t & 3;
      uint2 pk;
      pk.x = cvt_pk_bf16(v[i].x, v[i].y);
      pk.y = cvt_pk_bf16(v[i].z, v[i].w);
      *(uint2*)(xst + r * 16 + quad * 4) = pk;      // xstage idx = c*256 + n*16 + quad*4
    }
    if (t == 0) tn_lds[0] = (int)atomicAdd(ctr, 1u);
    __syncthreads();                    // bar1: xstage ready + next tn published
    int tn_next = tn_lds[0];
    if (tn_next < NTILES) {
      // ---- prefetch next tile; hides under transpose+conv+interp+GEMM ----
      int wt = tn_next % 6, bh = tn_next / 6;
      const float* xb = x + (size_t)(bh / 96) * 9437184 + (bh % 96) * 96 + wt * 16;
      #pragma unroll
      for (int i = 0; i < 8; ++i) {
        int r = (t >> 2) + i * 128, quad = t & 3;
        v[i] = *(const float4*)(xb + (size_t)r * 9216 + quad * 4);
      }
      __builtin_amdgcn_sched_barrier(0);   // pin load issue above the compute
    }

    // ---- transpose -> xs_t[pos][c] (b128 writes; stride 144B) ----
    #pragma unroll
    for (int i = 0; i < 4; ++i) {
      int item = t + 512 * i;                // 2048 = 256 pos x 8 cgroups
      int pos = item & 255, cg = item >> 8;
      short8 vv;
      #pragma unroll
      for (int jj = 0; jj < 8; ++jj) vv[jj] = (short)xst[(cg * 8 + jj) * 256 + pos];
      *(short8*)(smem + XT_OFF + pos * 144 + cg * 16) = vv;
    }
    __syncthreads();   // bar2: xs_t complete; xstage dead (offs overlays it)

    // ---- offsets conv via MFMA; offs produced & consumed by the SAME wave ----
    {
      f32x4 cacc[2] = {{0.f,0.f,0.f,0.f},{0.f,0.f,0.f,0.f}};
      const short8 zero = {0,0,0,0,0,0,0,0};
      #pragma unroll
      for (int ks = 0; ks < 6; ++ks) {
        short8 av = wfr[1536 + ks * 64 + l];
        int k3 = ks >> 1;
        #pragma unroll
        for (int nt2 = 0; nt2 < 2; ++nt2) {
          int n = wv * 2 + nt2;              // pos = n*16 + col
          int row = n + k3 - 1;
          bool valid = (row >= 0) && (row < 16);
          int rcl = min(max(row, 0), 15);
          short8 bv = *(short8*)(smem + XT_OFF + (rcl * 16 + col) * 144 + rg * 16 + (ks & 1) * 64);
          bv = valid ? bv : zero;
          cacc[nt2] = __builtin_amdgcn_mfma_f32_16x16x32_bf16(av, bv, cacc[nt2], 0, 0, 0);
        }
      }
      #pragma unroll
      for (int nt2 = 0; nt2 < 2; ++nt2) {
        int pos = (wv * 2 + nt2) * 16 + col;
        #pragma unroll
        for (int r = 0; r < 4; ++r) {
          int rowo = rg * 4 + r;
          if (rowo < 6) offs[rowo * 256 + pos] = cacc[nt2][r];
        }
      }
    }
    // no barrier: same-wave LDS ordering suffices (offs pos ranges are per-wave)

    // ---- interp params, per-lane in registers (all loop indices constant) ----
    float a0v[3][2], a1v[3][2]; int rb[3][2];
    #pragma unroll
    for (int k = 0; k < 3; ++k) {
      #pragma unroll
      for (int nt2 = 0; nt2 < 2; ++nt2) {
        int n = wv * 2 + nt2;
        int pos = n * 16 + col;
        float oy = offs[(2 * k) * 256 + pos] + b_off[2 * k];
        float ox = offs[(2 * k + 1) * 256 + pos] + b_off[2 * k + 1];
        float px = (float)(n - 1 + k) + ox;
        float x0f = floorf(px);
        float fx = px - x0f;
        int x0 = (int)x0f;
        float wy = fmaxf(0.f, 1.f - fabsf(oy));
        float wt1v = fx * wy;
        float wt0v = wy - wt1v;
        float a0, a1; int r0;
        if (x0 >= 0 && x0 < 15)  { r0 = x0; a0 = wt0v; a1 = wt1v; }
        else if (x0 == 15)       { r0 = 14; a0 = 0.f;  a1 = wt0v; }  // only row 15 (=x0)
        else if (x0 == -1)       { r0 = 0;  a0 = wt1v; a1 = 0.f;  }  // only row 0 (=x1)
        else                     { r0 = 0;  a0 = 0.f;  a1 = 0.f;  }
        a0v[k][nt2] = a0; a1v[k][nt2] = a1;
        rb[k][nt2] = (r0 * 16 + col) * 144;
      }
    }

    // ---- main GEMM: 64 o x 32 pos per wave, K=192; fully unrolled ----
    f32x4 acc[4][2];
    #pragma unroll
    for (int mt = 0; mt < 4; ++mt) {
      float4 bd = *(const float4*)(b_def + mt * 16 + rg * 4);
      #pragma unroll
      for (int nt2 = 0; nt2 < 2; ++nt2) {
        acc[mt][nt2][0] = bd.x; acc[mt][nt2][1] = bd.y;
        acc[mt][nt2][2] = bd.z; acc[mt][nt2][3] = bd.w;
      }
    }
    #pragma unroll
    for (int k3 = 0; k3 < 3; ++k3) {
      #pragma unroll
      for (int ks2 = 0; ks2 < 2; ++ks2) {
        int ks = k3 * 2 + ks2;
        short8 A[4];
        #pragma unroll
        for (int mt = 0; mt < 4; ++mt) A[mt] = wfr[(mt * 6 + ks) * 64 + l];
        #pragma unroll
        for (int nt2 = 0; nt2 < 2; ++nt2) {
          const char* base = smem + XT_OFF + rb[k3][nt2] + rg * 16 + ks2 * 64;
          u32x4 x0 = *(const u32x4*)base;
          u32x4 x1 = *(const u32x4*)(base + 2304);   // tap row r0+1 (16 pos x stride 144)
          f32x2 A0 = {a0v[k3][nt2], a0v[k3][nt2]};
          f32x2 A1 = {a1v[k3][nt2], a1v[k3][nt2]};
          union { uint32_t w[4]; short8 s; } bu;
          #pragma unroll
          for (int q = 0; q < 4; ++q) {
            uint32_t u0 = x0[q], u1 = x1[q];
            f32x2 X0 = { asf(u0 << 16), asf(u0 & 0xffff0000u) };
            f32x2 X1 = { asf(u1 << 16), asf(u1 & 0xffff0000u) };
            f32x2 R = A0 * X0 + A1 * X1;
            bu.w[q] = cvt_pk_bf16(R.x, R.y);
          }
          short8 bv = bu.s;
          #pragma unroll
          for (int mt = 0; mt < 4; ++mt)
            acc[mt][nt2] = __builtin_amdgcn_mfma_f32_16x16x32_bf16(A[mt], bv, acc[mt][nt2], 0, 0, 0);
        }
      }
    }

    // ---- epilogue: direct stores; partner half-line is being written ~now by
    //      whichever block grabbed the adjacent tn -> concurrent L2 merge ----
    {
      int wt = tn % 6, bh = tn / 6;
      float* ob = out + (size_t)(bh / 96) * 9437184 + (bh % 96) * 96 + wt * 16;
      #pragma unroll
      for (int mt = 0; mt < 4; ++mt) {
        #pragma unroll
        for (int nt2 = 0; nt2 < 2; ++nt2) {
          int n = wv * 2 + nt2;
          float* o0 = ob + (size_t)((mt * 16 + rg * 4) * 16 + n) * 9216 + col;
          #pragma unroll
          for (int r = 0; r < 4; ++r)
            o0[(size_t)r * 147456] = acc[mt][nt2][r];   // o stride = 16*9216
        }
      }
    }

    __syncthreads();   // bar3: offs/xs_t consumption done before next overwrite
    tn = tn_next;
  }
}

extern "C" void kernel_launch(void* const* d_in, const int* in_sizes, int n_in,
                              void* d_out, int out_size, void* d_ws, size_t ws_size,
                              hipStream_t stream) {
  (void)in_sizes; (void)n_in; (void)ws_size; (void)out_size;
  const float* x     = (const float*)d_in[0];
  const float* w_off = (const float*)d_in[1];
  const float* b_off = (const float*)d_in[2];
  const float* w_def = (const float*)d_in[3];
  const float* b_def = (const float*)d_in[4];
  float* out = (float*)d_out;
  short8* wfr = (short8*)d_ws;                               // 30720 B of frags
  unsigned int* ctr = (unsigned int*)((char*)d_ws + 30720);  // work counter

  (void)hipFuncSetAttribute((const void*)deform_main,
                            hipFuncAttributeMaxDynamicSharedMemorySize, LDS_BYTES);
  prep_kernel<<<dim3(8), dim3(256), 0, stream>>>(w_off, w_def, wfr, ctr);
  deform_main<<<dim3(512), dim3(512), LDS_BYTES, stream>>>(x, b_off, b_def, wfr, out, ctr);
}

// Round 13
// 225.345 us; speedup vs baseline: 1.0058x; 1.0020x over previous
//
#include <hip/hip_runtime.h>
#include <stdint.h>

// DeformableFusionAcrossFocus — round 18: r15 structure (best verified, 67.3µs) with
// the stage+transpose split into two 32-channel passes -> xstage 32KB->16KB ->
// LDS 53248 -> 3 blocks/CU (24 waves, 1.5 dispatch rounds vs 2.25).
// x:(2,64,16,96,96) f32 | w_off:(6,64,3) | b_off:(6) | w_def:(64,64,3) | b_def:(64) -> out f32
// Tile = (b,h,16w), grid 1152 x 512 thr, r15's XCD pair swizzle kept (verified:
// co-dispatched same-XCD partners merge half-lines: WRITE 81MB, FETCH halved to 39).
// Session law: half-line traffic merges ONLY between co-dispatched phase-locked
// partners (r9/r15 clean; r8/r13/r16/r17 de-phased variants all 1.5-2.2x dirty).
// This round isolates the occupancy axis with ALL compute code r15-verbatim:
// conv / interp / GEMM / epilogue untouched; only the staging is two half-passes
// (stage c0-31 -> bar -> transpose -> bar -> stage c32-63 -> bar -> transpose -> bar).
// No cross-barrier register holds (VGPR ~64, launch_bounds(512,6) for 6 waves/SIMD).
// Pre-committed readout: WRITE<=88MB -> pairing survives 3/CU, expect 48-58us.
// WRITE>=140MB -> 2/CU phase-lock is REQUIRED; r15 is the optimum -> resubmit it.

typedef __attribute__((ext_vector_type(8))) short short8;
typedef __attribute__((ext_vector_type(4))) float f32x4;
typedef __attribute__((ext_vector_type(2))) float f32x2;
typedef __attribute__((ext_vector_type(4))) unsigned int u32x4;

// LDS (bytes):
//  [0,36864)      xs_t bf16 [pos][72 shorts] (row stride 144B; 64 c used + 8 pad)
//  [36864,53248)  xstage bf16 [32 c-local][256 pos] (16KB; reused per half)
//  [36864,43008)  offs f32 [6][256] (overlays dead xstage; same-wave produce/consume)
#define XT_OFF   0
#define XG_OFF   36864
#define OFFS_OFF 36864
#define LDS_BYTES 53248   // 3 blocks/CU: 3*53248 = 159744 <= 163840

__device__ __forceinline__ short f2bf(float f) {
  union { float f; uint32_t u; } v; v.f = f;
  uint32_t r = (v.u + 0x7FFFu + ((v.u >> 16) & 1u)) >> 16;
  return (short)r;
}
__device__ __forceinline__ float asf(uint32_t u) {
  union { uint32_t u; float f; } v; v.u = u; return v.f;
}
__device__ __forceinline__ uint32_t cvt_pk_bf16(float lo, float hi) {
  uint32_t d;
  asm("v_cvt_pk_bf16_f32 %0, %1, %2" : "=v"(d) : "v"(lo), "v"(hi));
  return d;
}

// ---- prep: pre-swizzle w_def (frags [0,1536)) and w_off (frags [1536,1920)) into ws ----
__global__ __launch_bounds__(256) void prep_kernel(
    const float* __restrict__ w_off, const float* __restrict__ w_def, short8* __restrict__ ws)
{
  int gid = blockIdx.x * 256 + threadIdx.x;
  if (gid < 1536) {                      // q = (mt*6+ks)*64 + lane
    int mt = gid / 384, ks = (gid % 384) >> 6, ll = gid & 63;
    int m = mt * 16 + (ll & 15), rgq = ll >> 4;
    short8 v;
    #pragma unroll
    for (int jj = 0; jj < 8; ++jj) {
      int kk = ks * 32 + rgq * 8 + jj;
      int c = kk & 63, k3 = kk >> 6;
      v[jj] = f2bf(w_def[m * 192 + c * 3 + k3]);
    }
    ws[gid] = v;
  } else if (gid < 1920) {               // q = ks*64 + lane (rows 6..15 zero)
    int q = gid - 1536;
    int ks = q >> 6, ll = q & 63;
    int m = ll & 15, rgq = ll >> 4;
    short8 v;
    #pragma unroll
    for (int jj = 0; jj < 8; ++jj) {
      int kk = ks * 32 + rgq * 8 + jj;
      int c = kk & 63, k3 = kk >> 6;
      v[jj] = (m < 6) ? f2bf(w_off[m * 192 + c * 3 + k3]) : (short)0;
    }
    ws[gid] = v;
  }
}

__global__ __launch_bounds__(512, 6) void deform_main(
    const float* __restrict__ x, const float* __restrict__ b_off,
    const float* __restrict__ b_def, const short8* __restrict__ wfr,
    float* __restrict__ out)
{
  extern __shared__ char smem[];
  uint16_t* xst = (uint16_t*)(smem + XG_OFF);
  float* offs   = (float*)(smem + OFFS_OFF);

  const int t = threadIdx.x, wv = t >> 6, l = t & 63, col = l & 15, rg = l >> 4;
  const int p = blockIdx.x;
  const int tn = (p & ~15) | ((p & 7) << 1) | ((p >> 3) & 1);   // r7/r13/r15 pair swizzle
  const int wt = tn % 6, bh = tn / 6;
  const int h = bh % 96, b = bh / 96, w0 = wt * 16;
  const float* xb = x + (size_t)b * 9437184 + h * 96 + w0;

  // ---- stage+transpose in TWO 32-channel half-passes (xstage = 16KB) ----
  #pragma unroll
  for (int half = 0; half < 2; ++half) {
    // stage: c-local in [0,32) -> bf16 xstage [c-local][pos]; rows are full 64B lines
    #pragma unroll
    for (int i = 0; i < 4; ++i) {
      int r = (t >> 2) + i * 128, quad = t & 3;     // r local in [0,512); r = cl*16+n
      float4 v = *(const float4*)(xb + (size_t)(half * 512 + r) * 9216 + quad * 4);
      uint2 pk;
      pk.x = cvt_pk_bf16(v.x, v.y);
      pk.y = cvt_pk_bf16(v.z, v.w);
      *(uint2*)(xst + r * 16 + quad * 4) = pk;      // idx = cl*256 + n*16 + quad*4
    }
    __syncthreads();   // xstage(half) ready

    // transpose -> xs_t[pos][c] bytes [half*64, half*64+64) of each 144B row
    #pragma unroll
    for (int i = 0; i < 2; ++i) {
      int item = t + 512 * i;                // 1024 = 256 pos x 4 cgroups
      int pos = item & 255, cg = item >> 8;
      short8 vv;
      #pragma unroll
      for (int jj = 0; jj < 8; ++jj) vv[jj] = (short)xst[(cg * 8 + jj) * 256 + pos];
      *(short8*)(smem + XT_OFF + pos * 144 + (half * 4 + cg) * 16) = vv;
    }
    __syncthreads();   // transpose reads done; xstage reusable (half 0) / dead (half 1)
  }
  // xs_t complete; xstage dead (offs overlays it)

  // ---- offsets conv via MFMA; offs produced & consumed by the SAME wave ----
  {
    f32x4 cacc[2] = {{0.f,0.f,0.f,0.f},{0.f,0.f,0.f,0.f}};
    const short8 zero = {0,0,0,0,0,0,0,0};
    #pragma unroll
    for (int ks = 0; ks < 6; ++ks) {
      short8 av = wfr[1536 + ks * 64 + l];
      int k3 = ks >> 1;
      #pragma unroll
      for (int nt2 = 0; nt2 < 2; ++nt2) {
        int n = wv * 2 + nt2;              // pos = n*16 + col
        int row = n + k3 - 1;
        bool valid = (row >= 0) && (row < 16);
        int rcl = min(max(row, 0), 15);
        short8 bv = *(short8*)(smem + XT_OFF + (rcl * 16 + col) * 144 + rg * 16 + (ks & 1) * 64);
        bv = valid ? bv : zero;
        cacc[nt2] = __builtin_amdgcn_mfma_f32_16x16x32_bf16(av, bv, cacc[nt2], 0, 0, 0);
      }
    }
    #pragma unroll
    for (int nt2 = 0; nt2 < 2; ++nt2) {
      int pos = (wv * 2 + nt2) * 16 + col;
      #pragma unroll
      for (int r = 0; r < 4; ++r) {
        int rowo = rg * 4 + r;
        if (rowo < 6) offs[rowo * 256 + pos] = cacc[nt2][r];
      }
    }
  }
  // no barrier: same-wave LDS ordering suffices (offs pos ranges are per-wave)

  // ---- interp params, per-lane in registers (all loop indices constant) ----
  float a0v[3][2], a1v[3][2]; int rb[3][2];
  #pragma unroll
  for (int k = 0; k < 3; ++k) {
    #pragma unroll
    for (int nt2 = 0; nt2 < 2; ++nt2) {
      int n = wv * 2 + nt2;
      int pos = n * 16 + col;
      float oy = offs[(2 * k) * 256 + pos] + b_off[2 * k];
      float ox = offs[(2 * k + 1) * 256 + pos] + b_off[2 * k + 1];
      float px = (float)(n - 1 + k) + ox;
      float x0f = floorf(px);
      float fx = px - x0f;
      int x0 = (int)x0f;
      float wy = fmaxf(0.f, 1.f - fabsf(oy));
      float wt1v = fx * wy;
      float wt0v = wy - wt1v;
      float a0, a1; int r0;
      if (x0 >= 0 && x0 < 15)  { r0 = x0; a0 = wt0v; a1 = wt1v; }
      else if (x0 == 15)       { r0 = 14; a0 = 0.f;  a1 = wt0v; }  // only row 15 (=x0)
      else if (x0 == -1)       { r0 = 0;  a0 = wt1v; a1 = 0.f;  }  // only row 0 (=x1)
      else                     { r0 = 0;  a0 = 0.f;  a1 = 0.f;  }
      a0v[k][nt2] = a0; a1v[k][nt2] = a1;
      rb[k][nt2] = (r0 * 16 + col) * 144;
    }
  }

  // ---- main GEMM: 64 o x 32 pos per wave, K=192; fully unrolled ----
  f32x4 acc[4][2];
  #pragma unroll
  for (int mt = 0; mt < 4; ++mt) {
    float4 bd = *(const float4*)(b_def + mt * 16 + rg * 4);
    #pragma unroll
    for (int nt2 = 0; nt2 < 2; ++nt2) {
      acc[mt][nt2][0] = bd.x; acc[mt][nt2][1] = bd.y;
      acc[mt][nt2][2] = bd.z; acc[mt][nt2][3] = bd.w;
    }
  }
  #pragma unroll
  for (int k3 = 0; k3 < 3; ++k3) {
    #pragma unroll
    for (int ks2 = 0; ks2 < 2; ++ks2) {
      int ks = k3 * 2 + ks2;
      short8 A[4];
      #pragma unroll
      for (int mt = 0; mt < 4; ++mt) A[mt] = wfr[(mt * 6 + ks) * 64 + l];
      #pragma unroll
      for (int nt2 = 0; nt2 < 2; ++nt2) {
        const char* base = smem + XT_OFF + rb[k3][nt2] + rg * 16 + ks2 * 64;
        u32x4 x0 = *(const u32x4*)base;
        u32x4 x1 = *(const u32x4*)(base + 2304);   // tap row r0+1 (16 pos x stride 144)
        f32x2 A0 = {a0v[k3][nt2], a0v[k3][nt2]};
        f32x2 A1 = {a1v[k3][nt2], a1v[k3][nt2]};
        union { uint32_t w[4]; short8 s; } bu;
        #pragma unroll
        for (int q = 0; q < 4; ++q) {
          uint32_t u0 = x0[q], u1 = x1[q];
          f32x2 X0 = { asf(u0 << 16), asf(u0 & 0xffff0000u) };
          f32x2 X1 = { asf(u1 << 16), asf(u1 & 0xffff0000u) };
          f32x2 R = A0 * X0 + A1 * X1;
          bu.w[q] = cvt_pk_bf16(R.x, R.y);
        }
        short8 bv = bu.s;
        #pragma unroll
        for (int mt = 0; mt < 4; ++mt)
          acc[mt][nt2] = __builtin_amdgcn_mfma_f32_16x16x32_bf16(A[mt], bv, acc[mt][nt2], 0, 0, 0);
      }
    }
  }

  // ---- epilogue: direct stores; each 16-lane group writes one full 64B line,
  //      paired with co-dispatched block p^8's adjacent half (same XCD L2) ----
  float* ob = out + (size_t)b * 9437184 + h * 96 + w0;
  #pragma unroll
  for (int mt = 0; mt < 4; ++mt) {
    #pragma unroll
    for (int nt2 = 0; nt2 < 2; ++nt2) {
      int n = wv * 2 + nt2;
      float* o0 = ob + (size_t)((mt * 16 + rg * 4) * 16 + n) * 9216 + col;
      #pragma unroll
      for (int r = 0; r < 4; ++r)
        o0[(size_t)r * 147456] = acc[mt][nt2][r];   // o stride = 16*9216
    }
  }
}

extern "C" void kernel_launch(void* const* d_in, const int* in_sizes, int n_in,
                              void* d_out, int out_size, void* d_ws, size_t ws_size,
                              hipStream_t stream) {
  (void)in_sizes; (void)n_in; (void)ws_size; (void)out_size;
  const float* x     = (const float*)d_in[0];
  const float* w_off = (const float*)d_in[1];
  const float* b_off = (const float*)d_in[2];
  const float* w_def = (const float*)d_in[3];
  const float* b_def = (const float*)d_in[4];
  float* out = (float*)d_out;
  short8* wfr = (short8*)d_ws;   // 1920 * 16B = 30720 B of scratch

  (void)hipFuncSetAttribute((const void*)deform_main,
                            hipFuncAttributeMaxDynamicSharedMemorySize, LDS_BYTES);
  prep_kernel<<<dim3(8), dim3(256), 0, stream>>>(w_off, w_def, wfr);
  deform_main<<<dim3(1152), dim3(512), LDS_BYTES, stream>>>(x, b_off, b_def, wfr, out);
}